// Round 5
// baseline (115.543 us; speedup 1.0000x reference)
//
#include <hip/hip_runtime.h>

#define NSEG   4194304
#define BLOCK  256
#define TILE   4096                // per block
#define CHUNK  1024                // per scan pass (BLOCK * 4)
#define NCHUNK 4
#define NTILES (NSEG / TILE)       // 1024
#define WAVES  (BLOCK / 64)        // 4

static_assert(NTILES * TILE == NSEG, "tiling must cover N");

// Segment monoid: T = sum of angles, C/S = sum of cos/sin of segment-local
// inclusive cumulative angle. combine(a,b) = "a followed by b". Identity 0.
__device__ __forceinline__ void combineSeg(float aT, float aC, float aS,
                                           float bT, float bC, float bS,
                                           float& oT, float& oC, float& oS) {
    float s, c;
    __sincosf(aT, &s, &c);
    oT = aT + bT;
    oC = aC + c * bC - s * bS;
    oS = aS + s * bC + c * bS;
}

// ---------------- K1: per-tile (T, C, S) summaries, unit-stride loads ----------
__global__ __launch_bounds__(BLOCK) void k_tilesum(
        const float* __restrict__ vec, const float* __restrict__ vec2,
        float4* __restrict__ part) {
    const int c = blockIdx.y;
    const int b = blockIdx.x;
    const int t = threadIdx.x;
    const int lane = t & 63, wave = t >> 6;
    const float* __restrict__ v = c ? vec2 : vec;

    __shared__ float sW[NCHUNK][WAVES];
    __shared__ float sRC[WAVES], sRS[WAVES];

    const float4* __restrict__ p =
        reinterpret_cast<const float4*>(v + (size_t)b * TILE);
    float4 a[NCHUNK];
#pragma unroll
    for (int g = 0; g < NCHUNK; ++g) a[g] = p[g * (CHUNK / 4) + t];  // unit-stride

    float runT = 0.f, accC = 0.f, accS = 0.f;
#pragma unroll
    for (int g = 0; g < NCHUNK; ++g) {
        const float v0 = a[g].x, v1 = a[g].y, v2 = a[g].z, v3 = a[g].w;
        float s4 = v0 + v1 + v2 + v3;
        float incl = s4;
#pragma unroll
        for (int d = 1; d < 64; d <<= 1) {
            float o = __shfl_up(incl, d, 64);
            if (lane >= d) incl += o;
        }
        if (lane == 63) sW[g][wave] = incl;
        __syncthreads();
        float wpre = 0.f, tot = 0.f;
#pragma unroll
        for (int w = 0; w < WAVES; ++w) {
            float x = sW[g][w];
            if (w < wave) wpre += x;
            tot += x;
        }
        float run = runT + wpre + incl - s4;   // angle before this thread's elems
        float sn, cs;
        run += v0; __sincosf(run, &sn, &cs); accC += cs; accS += sn;
        run += v1; __sincosf(run, &sn, &cs); accC += cs; accS += sn;
        run += v2; __sincosf(run, &sn, &cs); accC += cs; accS += sn;
        run += v3; __sincosf(run, &sn, &cs); accC += cs; accS += sn;
        runT += tot;
    }
#pragma unroll
    for (int d = 32; d > 0; d >>= 1) {
        accC += __shfl_down(accC, d, 64);
        accS += __shfl_down(accS, d, 64);
    }
    if (lane == 0) { sRC[wave] = accC; sRS[wave] = accS; }
    __syncthreads();
    if (t == 0) {
        float Ct = 0.f, St = 0.f;
#pragma unroll
        for (int w = 0; w < WAVES; ++w) { Ct += sRC[w]; St += sRS[w]; }
        part[c * NTILES + b] = make_float4(runT, Ct, St, 0.f);
    }
}

// ---------------- K2: redundant summary-scan + emit, aligned dwordx4 stores ----
__global__ __launch_bounds__(BLOCK, 4) void k_emit(
        const float* __restrict__ vec, const float* __restrict__ vec2,
        const float* __restrict__ the0, const float* __restrict__ the02,
        const float* __restrict__ PS, const float* __restrict__ PE,
        const float* __restrict__ dl,
        const float4* __restrict__ part, float* __restrict__ out) {
    const int b = blockIdx.x;
    const int c = blockIdx.y;
    const int t = threadIdx.x;
    const int lane = t & 63, wave = t >> 6;
    const float* __restrict__ v = c ? vec2 : vec;

    __shared__ float sMT[WAVES], sMC[WAVES], sMS[WAVES];
    __shared__ float sPre[3];
    __shared__ float sW1[NCHUNK][WAVES];
    __shared__ float sWx[NCHUNK][WAVES], sWy[NCHUNK][WAVES];

    // Prefetch this tile's inputs (in flight during phase A).
    const float4* __restrict__ p =
        reinterpret_cast<const float4*>(v + (size_t)b * TILE);
    float4 a[NCHUNK];
#pragma unroll
    for (int g = 0; g < NCHUNK; ++g) a[g] = p[g * (CHUNK / 4) + t];

    // ---- Phase A: every block scans this curve's 1024 tile summaries and
    //      extracts tile b's exclusive prefix. Deterministic & identical.
    {
        const float4* __restrict__ pp = part + (size_t)c * NTILES;
        float aT[4], aC[4], aS[4];
        float T = 0.f, C = 0.f, S = 0.f;
#pragma unroll
        for (int j = 0; j < 4; ++j) {
            float4 d4 = pp[t * 4 + j];
            aT[j] = d4.x; aC[j] = d4.y; aS[j] = d4.z;
            combineSeg(T, C, S, aT[j], aC[j], aS[j], T, C, S);
        }
        float iT = T, iC = C, iS = S;
#pragma unroll
        for (int d = 1; d < 64; d <<= 1) {
            float oT = __shfl_up(iT, d, 64);
            float oC = __shfl_up(iC, d, 64);
            float oS = __shfl_up(iS, d, 64);
            if (lane >= d) combineSeg(oT, oC, oS, iT, iC, iS, iT, iC, iS);
        }
        float pT = __shfl_up(iT, 1, 64);
        float pC = __shfl_up(iC, 1, 64);
        float pS = __shfl_up(iS, 1, 64);
        float eT = (lane == 0) ? 0.f : pT;
        float eC = (lane == 0) ? 0.f : pC;
        float eS = (lane == 0) ? 0.f : pS;
        if (lane == 63) { sMT[wave] = iT; sMC[wave] = iC; sMS[wave] = iS; }
        __syncthreads();
        float wT = 0.f, wC = 0.f, wS = 0.f;
#pragma unroll
        for (int w = 0; w < WAVES; ++w) {
            if (w < wave) combineSeg(wT, wC, wS, sMT[w], sMC[w], sMS[w], wT, wC, wS);
        }
        float xT, xC, xS;   // exclusive prefix over tiles < 4t
        combineSeg(wT, wC, wS, eT, eC, eS, xT, xC, xS);

        if (b == 0) {
            if (t == 0) { sPre[0] = 0.f; sPre[1] = 0.f; sPre[2] = 0.f; }
        } else {
            const int q = (b - 1) >> 2;
            if (t == q) {
                float PT = xT, PC = xC, PZ = xS;
                const int m = (b - 1) & 3;
                for (int j = 0; j <= m; ++j)
                    combineSeg(PT, PC, PZ, aT[j], aC[j], aS[j], PT, PC, PZ);
                sPre[0] = PT; sPre[1] = PC; sPre[2] = PZ;
            }
        }
        __syncthreads();
    }

    const float t0 = c ? the02[0] : the0[0];
    const float sx = c ? PE[0] : PS[0];
    const float sy = c ? PE[1] : PS[1];
    const float dlv = dl[0];
    float s0, c0;
    __sincosf(t0, &s0, &c0);
    const float thPre = t0 + sPre[0];
    const float pxB = sx + dlv * (c0 * sPre[1] - s0 * sPre[2]);
    const float pyB = sy + dlv * (s0 * sPre[1] + c0 * sPre[2]);

    // ---- Phase B/C: per chunk: angle scan -> sincos -> (cos,sin) scan -> store.
    // Thread t owns OUTPUT indices gbase+4t..gbase+4t+3 (output o = pos after
    // step o-1; P(4t) == exclusive prefix) -> two aligned dwordx4 stores.
    float4* __restrict__ o4 =
        reinterpret_cast<float4*>(out + (size_t)c * (NSEG + 1) * 2);
    float runT = 0.f, carryC = 0.f, carryS = 0.f;
#pragma unroll
    for (int g = 0; g < NCHUNK; ++g) {
        const float v0 = a[g].x, v1 = a[g].y, v2 = a[g].z, v3 = a[g].w;
        float s4 = v0 + v1 + v2 + v3;
        float incl = s4;
#pragma unroll
        for (int d = 1; d < 64; d <<= 1) {
            float o = __shfl_up(incl, d, 64);
            if (lane >= d) incl += o;
        }
        if (lane == 63) sW1[g][wave] = incl;
        __syncthreads();
        float wpre = 0.f, totA = 0.f;
#pragma unroll
        for (int w = 0; w < WAVES; ++w) {
            float x = sW1[g][w];
            if (w < wave) wpre += x;
            totA += x;
        }
        float run = thPre + runT + wpre + incl - s4;
        float cs[4], sn[4];
        run += v0; __sincosf(run, &sn[0], &cs[0]);
        run += v1; __sincosf(run, &sn[1], &cs[1]);
        run += v2; __sincosf(run, &sn[2], &cs[2]);
        run += v3; __sincosf(run, &sn[3], &cs[3]);
        runT += totA;

        float sC4 = cs[0] + cs[1] + cs[2] + cs[3];
        float sS4 = sn[0] + sn[1] + sn[2] + sn[3];
        float ix = sC4, iy = sS4;
#pragma unroll
        for (int d = 1; d < 64; d <<= 1) {
            float ox = __shfl_up(ix, d, 64);
            float oy = __shfl_up(iy, d, 64);
            if (lane >= d) { ix += ox; iy += oy; }
        }
        if (lane == 63) { sWx[g][wave] = ix; sWy[g][wave] = iy; }
        __syncthreads();
        float wpx = 0.f, wpy = 0.f, totC = 0.f, totS = 0.f;
#pragma unroll
        for (int w = 0; w < WAVES; ++w) {
            float xx = sWx[g][w], yy = sWy[g][w];
            if (w < wave) { wpx += xx; wpy += yy; }
            totC += xx; totS += yy;
        }
        const float x0 = pxB + dlv * (carryC + wpx + ix - sC4);
        const float y0 = pyB + dlv * (carryS + wpy + iy - sS4);
        const float x1 = x0 + dlv * cs[0], y1 = y0 + dlv * sn[0];
        const float x2 = x1 + dlv * cs[1], y2 = y1 + dlv * sn[1];
        const float x3 = x2 + dlv * cs[2], y3 = y2 + dlv * sn[2];
        carryC += totC; carryS += totS;

        const size_t obase = ((size_t)b * TILE + (size_t)g * CHUNK) / 2 + 2 * t;
        o4[obase + 0] = make_float4(x0, y0, x1, y1);
        o4[obase + 1] = make_float4(x2, y2, x3, y3);

        if (g == NCHUNK - 1 && b == NTILES - 1 && t == BLOCK - 1) {
            // final output index NSEG = position after the very last step
            reinterpret_cast<float2*>(o4)[NSEG] =
                make_float2(x3 + dlv * cs[3], y3 + dlv * sn[3]);
        }
    }
}

extern "C" void kernel_launch(void* const* d_in, const int* in_sizes, int n_in,
                              void* d_out, int out_size, void* d_ws, size_t ws_size,
                              hipStream_t stream) {
    const float* vec   = (const float*)d_in[0];
    const float* vec2  = (const float*)d_in[1];
    const float* the0  = (const float*)d_in[2];
    const float* the02 = (const float*)d_in[3];
    const float* PS    = (const float*)d_in[4];
    const float* PE    = (const float*)d_in[5];
    const float* dl    = (const float*)d_in[6];
    float* out = (float*)d_out;
    float4* part = (float4*)d_ws;   // 2 * 1024 float4 = 32 KB

    dim3 grid(NTILES, 2);
    k_tilesum<<<grid, BLOCK, 0, stream>>>(vec, vec2, part);
    k_emit<<<grid, BLOCK, 0, stream>>>(vec, vec2, the0, the02, PS, PE, dl,
                                       part, out);
}